// Round 7
// baseline (279.134 us; speedup 1.0000x reference)
//
#include <hip/hip_runtime.h>
#include <math.h>

#define NTOK  16384
#define NW6   (NTOK * 6)
#define D_    2048
#define D4_   512

#define CHDIM 64           // dims staged per chunk
#define LDSTR 257          // dword stride between dim-rows (2-way banks = free)

// ---------------- Phase 1: partial scores, lane = token ----------------
// Block: 256 threads = 256 tokens, one D-segment. x is staged transposed
// through LDS (coalesced global -> per-lane token-major reads). W is read
// via wave-uniform addresses -> scalar loads into SGPRs; each lane keeps 18
// scalar accumulators. No cross-lane reduction needed.
template <int NSEG>
__global__ __launch_bounds__(256) void scores_kernel(
    const float* __restrict__ x,
    const float* __restrict__ We,
    const float* __restrict__ Wg,
    float* __restrict__ scores)
{
    constexpr int SEGD = D_ / NSEG;       // dims per segment
    constexpr int NCH  = SEGD / CHDIM;    // chunks per segment
    __shared__ float xs[CHDIM * LDSTR];   // 65,792 B

    const int tid   = threadIdx.x;
    const int seg   = blockIdx.x % NSEG;
    const int strip = blockIdx.x / NSEG;
    const int dimbase = seg * SEGD;

    const float4* __restrict__ x4 = reinterpret_cast<const float4*>(x);

    float acc[18];
#pragma unroll
    for (int e = 0; e < 18; ++e) acc[e] = 0.f;

    const int lrow = tid >> 4;   // 0..15
    const int lcol = tid & 15;   // float4 column within chunk

    for (int ch = 0; ch < NCH; ++ch) {
        // ---- stage 256 tokens x 64 dims, transposed ----
        const int gq = (dimbase >> 2) + ch * (CHDIM / 4);
#pragma unroll
        for (int i = 0; i < 16; ++i) {
            const int row = i * 16 + lrow;                 // local token
            const float4 v = x4[(size_t)(strip * 256 + row) * D4_ + gq + lcol];
            const int d = lcol * 4;
            xs[(d + 0) * LDSTR + row] = v.x;
            xs[(d + 1) * LDSTR + row] = v.y;
            xs[(d + 2) * LDSTR + row] = v.z;
            xs[(d + 3) * LDSTR + row] = v.w;
        }
        __syncthreads();

        // ---- compute: 1 dword LDS read feeds 18 FMAs ----
        const int gd = dimbase + ch * CHDIM;
#pragma unroll 2
        for (int q = 0; q < CHDIM / 4; ++q) {
            const float x0 = xs[(4 * q + 0) * LDSTR + tid];
            const float x1 = xs[(4 * q + 1) * LDSTR + tid];
            const float x2 = xs[(4 * q + 2) * LDSTR + tid];
            const float x3 = xs[(4 * q + 3) * LDSTR + tid];
#pragma unroll
            for (int e = 0; e < 18; ++e) {
                const float* wr = (e < 16) ? (We + (size_t)e * D_)
                                           : (Wg + (size_t)(e - 16) * D_);
                const float4 w = *reinterpret_cast<const float4*>(wr + gd + 4 * q);
                acc[e] += w.x * x0 + w.y * x1 + w.z * x2 + w.w * x3;
            }
        }
        __syncthreads();
    }

    const int tok = strip * 256 + tid;
#pragma unroll
    for (int e = 0; e < 18; ++e)
        scores[(size_t)(seg * 18 + e) * NTOK + tok] = acc[e];
}

// ---------------- Phase 2: combine segments + routing + aux ----------------
template <int NSEG>
__global__ __launch_bounds__(256) void route_kernel(
    const float* __restrict__ scores,
    float* __restrict__ out,
    unsigned int* __restrict__ gcounts)
{
    __shared__ unsigned int lcnt[16];
    const int tid = threadIdx.x;
    if (tid < 16) lcnt[tid] = 0u;
    __syncthreads();

    const int tok = blockIdx.x * 256 + tid;

    float s[18];
#pragma unroll
    for (int e = 0; e < 18; ++e) s[e] = 0.f;
    for (int g = 0; g < NSEG; ++g) {
#pragma unroll
        for (int e = 0; e < 18; ++e)
            s[e] += scores[(size_t)(g * 18 + e) * NTOK + tok];
    }

    const float g0 = 1.f / (1.f + expf(-s[16]));
    const float g1 = 1.f / (1.f + expf(-s[17]));

    // --- Group A: experts 0..7, top-1 of softmax ---
    int aidx = 0; float amax = s[0];
#pragma unroll
    for (int i = 1; i < 8; ++i)
        if (s[i] > amax) { amax = s[i]; aidx = i; }
    float asum = 0.f;
#pragma unroll
    for (int i = 0; i < 8; ++i) asum += expf(s[i] - amax);
    const float a_best = 1.f / asum;

    // --- Group B: experts 8..11, top-1, gated by g0 ---
    int bidx = 0; float bmax = s[8];
#pragma unroll
    for (int i = 1; i < 4; ++i)
        if (s[8 + i] > bmax) { bmax = s[8 + i]; bidx = i; }
    float bsum = 0.f;
#pragma unroll
    for (int i = 0; i < 4; ++i) bsum += expf(s[8 + i] - bmax);
    const float b_w = (g0 > 0.15f) ? ((1.f / bsum) * g0) : 0.f;

    // --- Group C: experts 12..15, top-2 of softmax, gated by g1 ---
    int c1 = 0; float cmax = s[12];
#pragma unroll
    for (int i = 1; i < 4; ++i)
        if (s[12 + i] > cmax) { cmax = s[12 + i]; c1 = i; }
    float csum = 0.f;
#pragma unroll
    for (int i = 0; i < 4; ++i) csum += expf(s[12 + i] - cmax);
    int c2 = -1; float c2v = -1e30f;
#pragma unroll
    for (int i = 0; i < 4; ++i)
        if (i != c1 && s[12 + i] > c2v) { c2v = s[12 + i]; c2 = i; }
    const float cg   = (g1 > 0.15f) ? g1 : 0.f;
    const float c_w1 = (1.f / csum) * cg;
    const float c_w2 = (expf(c2v - cmax) / csum) * cg;

    // --- normalize and write ---
    const float inv = 1.f / (a_best + b_w + c_w1 + c_w2 + 1e-8f);
    float2* ow = reinterpret_cast<float2*>(out + (size_t)tok * 6);
    ow[0] = make_float2(a_best * inv, b_w * inv);
    ow[1] = make_float2(c_w1 * inv, c_w2 * inv);
    ow[2] = make_float2(0.f, 0.f);
    float2* oi = reinterpret_cast<float2*>(out + NW6 + (size_t)tok * 6);
    oi[0] = make_float2((float)aidx, (float)(8 + bidx));
    oi[1] = make_float2((float)(12 + c1), (float)(12 + c2));
    oi[2] = make_float2(0.f, 0.f);

    atomicAdd(&lcnt[aidx], 1u);
    atomicAdd(&lcnt[8 + bidx], 1u);
    atomicAdd(&lcnt[12 + c1], 1u);
    atomicAdd(&lcnt[12 + c2], 1u);

    __syncthreads();
    if (tid < 16) {
        const unsigned int c = lcnt[tid];
        if (c) atomicAdd(&gcounts[tid], c);
    }
    __syncthreads();

    // Last-block ticket: aux loss. Reference bincount counts the 2 zero-pad
    // indices per token -> expert 0 gets +2*NTOK; total = 6*NTOK.
    if (tid == 0) {
        __threadfence();
        const unsigned int t = atomicAdd(&gcounts[16], 1u);
        if (t == gridDim.x - 1) {
            const float total = 6.0f * (float)NTOK;
            const float uni = 1.0f / 16.0f;
            float aux = 0.f;
            for (int e = 0; e < 16; ++e) {
                float c = (float)atomicAdd(&gcounts[e], 0u)
                          + (e == 0 ? 2.0f * (float)NTOK : 0.0f);
                aux += uni * (logf(uni) - logf(c / total));
            }
            out[2 * NW6] = aux * 0.01f;
        }
    }
}

extern "C" void kernel_launch(void* const* d_in, const int* in_sizes, int n_in,
                              void* d_out, int out_size, void* d_ws, size_t ws_size,
                              hipStream_t stream)
{
    const float* x  = (const float*)d_in[0];   // (4,4096,2048)
    const float* We = (const float*)d_in[1];   // (16,2048)
    const float* Wg = (const float*)d_in[2];   // (2,2048)
    float* out = (float*)d_out;

    const size_t scores8 = (size_t)8 * 18 * NTOK * 4;   // 9.44 MB
    const size_t scores4 = (size_t)4 * 18 * NTOK * 4;   // 4.72 MB
    float* scores = (float*)d_ws;

    if (ws_size >= scores8 + 128) {
        unsigned int* counts = (unsigned int*)((char*)d_ws + scores8);
        hipMemsetAsync(counts, 0, 17 * sizeof(unsigned int), stream);
        scores_kernel<8><<<dim3(64 * 8), 256, 0, stream>>>(x, We, Wg, scores);
        route_kernel<8><<<dim3(NTOK / 256), 256, 0, stream>>>(scores, out, counts);
    } else {
        unsigned int* counts = (unsigned int*)((char*)d_ws + scores4);
        hipMemsetAsync(counts, 0, 17 * sizeof(unsigned int), stream);
        scores_kernel<4><<<dim3(64 * 4), 256, 0, stream>>>(x, We, Wg, scores);
        route_kernel<4><<<dim3(NTOK / 256), 256, 0, stream>>>(scores, out, counts);
    }
}

// Round 8
// 214.005 us; speedup vs baseline: 1.3043x; 1.3043x over previous
//
#include <hip/hip_runtime.h>
#include <math.h>

#define NTOK  16384
#define NW6   (NTOK * 6)
#define NSEG  4
#define SEGD4 128              // 512 dims / 4 per float4
#define D4    512              // full row in float4
#define SCORES_FLOATS (NSEG * 18 * NTOK)   // 4.72 MB

#define DOT4(a, b) ((a).x*(b).x + (a).y*(b).y + (a).z*(b).z + (a).w*(b).w)

// DPP row_shl sum-tree: lane i adds lane i+N (out-of-range -> 0). After the
// 4 steps lane 0 of each 16-lane row holds the full row sum. Pure VALU.
template <int CTRL>
__device__ __forceinline__ float dpp_add(float v) {
    int moved = __builtin_amdgcn_update_dpp(0, __float_as_int(v),
                                            CTRL, 0xF, 0xF, true);
    return v + __int_as_float(moved);
}
__device__ __forceinline__ float row_reduce16(float v) {
    v = dpp_add<0x108>(v);   // row_shl:8
    v = dpp_add<0x104>(v);   // row_shl:4
    v = dpp_add<0x102>(v);   // row_shl:2
    v = dpp_add<0x101>(v);   // row_shl:1
    return v;                // full sum valid at lane 0 of each row of 16
}

// ---------------- Phase 1: partial scores per D-segment ----------------
// R6 structure (wave = 4 groups x 16 lanes, group = 4 tokens, 36 KB W-segment
// in LDS) with explicit register blocking:
//  - launch_bounds(256,2): VGPR cap 256 (R6's cap starved it to 1 buffer)
//  - w[18]: all 18 ds_read_b128 issued back-to-back, pipelined
//  - x double-buffer: next iter's 4 float4 issued at top of body
__global__ __launch_bounds__(256, 2) void scores_kernel(
    const float* __restrict__ x,
    const float* __restrict__ We,
    const float* __restrict__ Wg,
    float* __restrict__ scores)
{
    __shared__ float4 wlds[18 * SEGD4];   // 36,864 B

    const int tid   = threadIdx.x;
    const int seg   = blockIdx.x & 3;
    const int strip = blockIdx.x >> 2;

    const float4* __restrict__ x4  = reinterpret_cast<const float4*>(x);
    const float4* __restrict__ We4 = reinterpret_cast<const float4*>(We);
    const float4* __restrict__ Wg4 = reinterpret_cast<const float4*>(Wg);

    // Stage the 18 x 512-dim W segment into LDS (coalesced, conflict-free).
#pragma unroll
    for (int k = 0; k < 9; ++k) {
        const int idx = k * 256 + tid;        // 0..2303 float4
        const int e = idx >> 7;               // 0..17
        const int d = idx & 127;
        const float4* src = (e < 16) ? (We4 + (size_t)e * D4)
                                     : (Wg4 + (size_t)(e - 16) * D4);
        wlds[idx] = src[seg * SEGD4 + d];
    }
    __syncthreads();

    const int wave = tid >> 6;
    const int lane = tid & 63;
    const int grp  = lane >> 4;
    const int l16  = lane & 15;
    const int tokbase = strip * 64 + wave * 16 + grp * 4;

    const float4* __restrict__ xr0 = x4 + (size_t)(tokbase + 0) * D4 + seg * SEGD4;
    const float4* __restrict__ xr1 = x4 + (size_t)(tokbase + 1) * D4 + seg * SEGD4;
    const float4* __restrict__ xr2 = x4 + (size_t)(tokbase + 2) * D4 + seg * SEGD4;
    const float4* __restrict__ xr3 = x4 + (size_t)(tokbase + 3) * D4 + seg * SEGD4;

    float acc0[18], acc1[18], acc2[18], acc3[18];
#pragma unroll
    for (int e = 0; e < 18; ++e) { acc0[e]=0.f; acc1[e]=0.f; acc2[e]=0.f; acc3[e]=0.f; }

    // Prologue: x for iteration 0.
    float4 xa0 = xr0[l16], xa1 = xr1[l16], xa2 = xr2[l16], xa3 = xr3[l16];

    // 8 iters x 64 dims. Body: prefetch next x (4 glb), load w[18] (18 LDS
    // b128, pipelined), 288 FMA, rotate.
#pragma unroll 2
    for (int it = 0; it < 8; ++it) {
        const int off  = it * 16 + l16;
        const int noff = (it < 7) ? (off + 16) : off;   // last iter: benign reload
        float4 nx0 = xr0[noff];
        float4 nx1 = xr1[noff];
        float4 nx2 = xr2[noff];
        float4 nx3 = xr3[noff];

        float4 w[18];
#pragma unroll
        for (int e = 0; e < 18; ++e) w[e] = wlds[e * SEGD4 + off];

#pragma unroll
        for (int e = 0; e < 18; ++e) {
            acc0[e] += DOT4(w[e], xa0);
            acc1[e] += DOT4(w[e], xa1);
            acc2[e] += DOT4(w[e], xa2);
            acc3[e] += DOT4(w[e], xa3);
        }
        xa0 = nx0; xa1 = nx1; xa2 = nx2; xa3 = nx3;
    }

    // VALU row-reduce: lane 0 of each 16-lane group gets each full sum.
#pragma unroll
    for (int e = 0; e < 18; ++e) {
        acc0[e] = row_reduce16(acc0[e]);
        acc1[e] = row_reduce16(acc1[e]);
        acc2[e] = row_reduce16(acc2[e]);
        acc3[e] = row_reduce16(acc3[e]);
    }

    if (l16 == 0) {
#pragma unroll
        for (int e = 0; e < 18; ++e) {
            float* p = scores + (size_t)(seg * 18 + e) * NTOK + tokbase;
            p[0] = acc0[e];
            p[1] = acc1[e];
            p[2] = acc2[e];
            p[3] = acc3[e];
        }
    }
}

// ---------------- Phase 2: combine segments + routing + aux ----------------
__global__ __launch_bounds__(256) void route_kernel(
    const float* __restrict__ scores,
    float* __restrict__ out,
    unsigned int* __restrict__ gcounts)
{
    __shared__ unsigned int lcnt[16];
    const int tid = threadIdx.x;
    if (tid < 16) lcnt[tid] = 0u;
    __syncthreads();

    const int tok = blockIdx.x * 256 + tid;

    float s[18];
#pragma unroll
    for (int e = 0; e < 18; ++e) {
        s[e] = scores[(size_t)(0 * 18 + e) * NTOK + tok]
             + scores[(size_t)(1 * 18 + e) * NTOK + tok]
             + scores[(size_t)(2 * 18 + e) * NTOK + tok]
             + scores[(size_t)(3 * 18 + e) * NTOK + tok];
    }

    const float g0 = 1.f / (1.f + expf(-s[16]));
    const float g1 = 1.f / (1.f + expf(-s[17]));

    // --- Group A: experts 0..7, top-1 of softmax ---
    int aidx = 0; float amax = s[0];
#pragma unroll
    for (int i = 1; i < 8; ++i)
        if (s[i] > amax) { amax = s[i]; aidx = i; }
    float asum = 0.f;
#pragma unroll
    for (int i = 0; i < 8; ++i) asum += expf(s[i] - amax);
    const float a_best = 1.f / asum;

    // --- Group B: experts 8..11, top-1, gated by g0 ---
    int bidx = 0; float bmax = s[8];
#pragma unroll
    for (int i = 1; i < 4; ++i)
        if (s[8 + i] > bmax) { bmax = s[8 + i]; bidx = i; }
    float bsum = 0.f;
#pragma unroll
    for (int i = 0; i < 4; ++i) bsum += expf(s[8 + i] - bmax);
    const float b_w = (g0 > 0.15f) ? ((1.f / bsum) * g0) : 0.f;

    // --- Group C: experts 12..15, top-2 of softmax, gated by g1 ---
    int c1 = 0; float cmax = s[12];
#pragma unroll
    for (int i = 1; i < 4; ++i)
        if (s[12 + i] > cmax) { cmax = s[12 + i]; c1 = i; }
    float csum = 0.f;
#pragma unroll
    for (int i = 0; i < 4; ++i) csum += expf(s[12 + i] - cmax);
    int c2 = -1; float c2v = -1e30f;
#pragma unroll
    for (int i = 0; i < 4; ++i)
        if (i != c1 && s[12 + i] > c2v) { c2v = s[12 + i]; c2 = i; }
    const float cg   = (g1 > 0.15f) ? g1 : 0.f;
    const float c_w1 = (1.f / csum) * cg;
    const float c_w2 = (expf(c2v - cmax) / csum) * cg;

    // --- normalize and write ---
    const float inv = 1.f / (a_best + b_w + c_w1 + c_w2 + 1e-8f);
    float2* ow = reinterpret_cast<float2*>(out + (size_t)tok * 6);
    ow[0] = make_float2(a_best * inv, b_w * inv);
    ow[1] = make_float2(c_w1 * inv, c_w2 * inv);
    ow[2] = make_float2(0.f, 0.f);
    float2* oi = reinterpret_cast<float2*>(out + NW6 + (size_t)tok * 6);
    oi[0] = make_float2((float)aidx, (float)(8 + bidx));
    oi[1] = make_float2((float)(12 + c1), (float)(12 + c2));
    oi[2] = make_float2(0.f, 0.f);

    atomicAdd(&lcnt[aidx], 1u);
    atomicAdd(&lcnt[8 + bidx], 1u);
    atomicAdd(&lcnt[12 + c1], 1u);
    atomicAdd(&lcnt[12 + c2], 1u);

    __syncthreads();
    if (tid < 16) {
        const unsigned int c = lcnt[tid];
        if (c) atomicAdd(&gcounts[tid], c);
    }
    __syncthreads();

    // Last-block ticket: aux loss. Reference bincount counts the 2 zero-pad
    // indices per token -> expert 0 gets +2*NTOK; total = 6*NTOK.
    if (tid == 0) {
        __threadfence();
        const unsigned int t = atomicAdd(&gcounts[16], 1u);
        if (t == gridDim.x - 1) {
            const float total = 6.0f * (float)NTOK;
            const float uni = 1.0f / 16.0f;
            float aux = 0.f;
            for (int e = 0; e < 16; ++e) {
                float c = (float)atomicAdd(&gcounts[e], 0u)
                          + (e == 0 ? 2.0f * (float)NTOK : 0.0f);
                aux += uni * (logf(uni) - logf(c / total));
            }
            out[2 * NW6] = aux * 0.01f;
        }
    }
}

extern "C" void kernel_launch(void* const* d_in, const int* in_sizes, int n_in,
                              void* d_out, int out_size, void* d_ws, size_t ws_size,
                              hipStream_t stream)
{
    const float* x  = (const float*)d_in[0];   // (4,4096,2048)
    const float* We = (const float*)d_in[1];   // (16,2048)
    const float* Wg = (const float*)d_in[2];   // (2,2048)
    float* out = (float*)d_out;

    float* scores = (float*)d_ws;                          // 4.72 MB
    unsigned int* counts = (unsigned int*)((char*)d_ws + SCORES_FLOATS * 4);

    hipMemsetAsync(counts, 0, 17 * sizeof(unsigned int), stream);

    // Phase 1: 256 token-strips x 4 D-segments.
    scores_kernel<<<dim3(1024), 256, 0, stream>>>(x, We, Wg, scores);
    // Phase 2 (stream-ordered after phase 1).
    route_kernel<<<dim3(NTOK / 256), 256, 0, stream>>>(scores, out, counts);
}